// Round 1
// baseline (262.122 us; speedup 1.0000x reference)
//
#include <hip/hip_runtime.h>
#include <stdint.h>

#define CIN   256
#define COUT  128
#define HH    128
#define WW    128
#define NIMG  16

typedef unsigned long long u64;

// ---------------------------------------------------------------------------
// Pack sign bits of x: px[(n*HH + h)*WW + w][word 0..3], bit (c&63) of word
// (c>>6) is (x[n][c][h][w] > 0). Layout: position-major, 4 u64 per position.
// Memory-bound: reads 256 MiB fp32, writes 8 MiB packed.
// ---------------------------------------------------------------------------
__global__ __launch_bounds__(256) void pack_x_kernel(const float* __restrict__ x,
                                                     u64* __restrict__ px) {
    int t = blockIdx.x * 256 + threadIdx.x;   // position id: n*16384 + h*128 + w
    int w = t & (WW - 1);
    int h = (t >> 7) & (HH - 1);
    int n = t >> 14;
    const float* xp = x + (size_t)n * CIN * HH * WW + (size_t)h * WW + w;
    u64 words[4];
#pragma unroll
    for (int wd = 0; wd < 4; ++wd) {
        u64 acc = 0;
#pragma unroll 16
        for (int cc = 0; cc < 64; ++cc) {
            float v = xp[(size_t)(wd * 64 + cc) * (HH * WW)];
            acc |= (u64)(v > 0.0f) << cc;
        }
        words[wd] = acc;
    }
    ulonglong2* o = reinterpret_cast<ulonglong2*>(px + (size_t)t * 4);
    o[0] = make_ulonglong2(words[0], words[1]);
    o[1] = make_ulonglong2(words[2], words[3]);
}

// ---------------------------------------------------------------------------
// Pack weight sign bits + alpha. One block per co; thread = channel c.
// pw[co*36 + tap*4 + word], tap = kh*3+kw. Ballot across the wave packs 64
// channels' sign bits in one instruction. alpha[co] = mean|W| over 2304.
// ---------------------------------------------------------------------------
__global__ __launch_bounds__(256) void pack_w_kernel(const float* __restrict__ wt,
                                                     u64* __restrict__ pw,
                                                     float* __restrict__ alpha) {
    int co = blockIdx.x;
    int c  = threadIdx.x;        // 0..255 = input channel
    int lane = c & 63;
    int word = c >> 6;
    const float* wp = wt + ((size_t)co * CIN + c) * 9;
    float vals[9];
    float asum = 0.0f;
#pragma unroll
    for (int k = 0; k < 9; ++k) { vals[k] = wp[k]; asum += fabsf(vals[k]); }
#pragma unroll
    for (int k = 0; k < 9; ++k) {
        u64 m = __ballot(vals[k] > 0.0f);
        if (lane == 0) pw[co * 36 + k * 4 + word] = m;
    }
    __shared__ float red[4];
    for (int off = 32; off > 0; off >>= 1) asum += __shfl_down(asum, off);
    if (lane == 0) red[word] = asum;
    __syncthreads();
    if (c == 0) alpha[co] = (red[0] + red[1] + red[2] + red[3]) * (1.0f / 2304.0f);
}

// ---------------------------------------------------------------------------
// XNOR conv: each thread owns one (n,h,w), holds the 9 neighbor positions'
// 4 packed words in VGPRs (36 u64 = 72 VGPR), loops over all 128 co.
// All packed weights (36 KiB) staged in LDS; reads are wave-uniform
// broadcasts (ds_read_b128, conflict-free). Border taps: per-tap AND mask
// (uniform code, no divergent branches in the hot loop).
// out[n][co][h][w] = (256*nv - 2*mismatch) * alpha[w]   (alpha by WIDTH!)
// ---------------------------------------------------------------------------
__global__ __launch_bounds__(256, 4) void conv_kernel(const u64* __restrict__ px,
                                                      const u64* __restrict__ pw,
                                                      const float* __restrict__ alpha,
                                                      float* __restrict__ out) {
    __shared__ __align__(16) u64 wlds[COUT * 36];   // 36 KiB
    for (int i = threadIdx.x; i < COUT * 36; i += 256) wlds[i] = pw[i];
    __syncthreads();

    int tid = threadIdx.x;
    int w  = tid & (WW - 1);
    int hh = tid >> 7;                 // 0/1: two rows per block
    int bid = blockIdx.x;              // 0..1023 = n*64 + hpair
    int h = ((bid & 63) << 1) | hh;
    int n = bid >> 6;

    u64 xin[9][4];
    uint32_t vmask[9];
    int nv = 0;
#pragma unroll
    for (int dh = -1; dh <= 1; ++dh) {
#pragma unroll
        for (int dw = -1; dw <= 1; ++dw) {
            int k = (dh + 1) * 3 + (dw + 1);
            int hn = h + dh, wn = w + dw;
            bool valid = (hn >= 0) && (hn < HH) && (wn >= 0) && (wn < WW);
            vmask[k] = valid ? 0xFFFFFFFFu : 0u;
            nv += valid ? 1 : 0;
            if (valid) {
                const ulonglong2* p = reinterpret_cast<const ulonglong2*>(
                    px + ((size_t)(n * HH + hn) * WW + wn) * 4);
                ulonglong2 a = p[0], b = p[1];
                xin[k][0] = a.x; xin[k][1] = a.y; xin[k][2] = b.x; xin[k][3] = b.y;
            } else {
                xin[k][0] = 0; xin[k][1] = 0; xin[k][2] = 0; xin[k][3] = 0;
            }
        }
    }
    int base = nv << 8;                 // 256 * valid taps
    float aw = alpha[w];                // faithful broadcast: alpha[WIDTH]
    float* op = out + (size_t)n * COUT * HH * WW + (size_t)h * WW + w;

    for (int co = 0; co < COUT; ++co) {
        const ulonglong2* wp2 = reinterpret_cast<const ulonglong2*>(&wlds[co * 36]);
        int M = 0;
#pragma unroll
        for (int k = 0; k < 9; ++k) {
            ulonglong2 wa = wp2[k * 2];
            ulonglong2 wb = wp2[k * 2 + 1];
            int c = __popcll(xin[k][0] ^ wa.x);
            c += __popcll(xin[k][1] ^ wa.y);
            c += __popcll(xin[k][2] ^ wb.x);
            c += __popcll(xin[k][3] ^ wb.y);
            M += c & (int)vmask[k];     // zero out OOB taps
        }
        op[(size_t)co * (HH * WW)] = (float)(base - 2 * M) * aw;
    }
}

extern "C" void kernel_launch(void* const* d_in, const int* in_sizes, int n_in,
                              void* d_out, int out_size, void* d_ws, size_t ws_size,
                              hipStream_t stream) {
    const float* x  = (const float*)d_in[0];
    const float* wt = (const float*)d_in[1];
    float* out = (float*)d_out;

    char* ws = (char*)d_ws;
    const size_t PX_BYTES = (size_t)NIMG * HH * WW * 4 * sizeof(u64);  // 8 MiB
    const size_t PW_BYTES = (size_t)COUT * 36 * sizeof(u64);           // 36 KiB
    if (ws_size < PX_BYTES + PW_BYTES + 512) return;  // workspace too small
    u64*   px    = (u64*)ws;
    u64*   pw    = (u64*)(ws + PX_BYTES);
    float* alpha = (float*)(ws + PX_BYTES + PW_BYTES);

    pack_x_kernel<<<NIMG * HH * WW / 256, 256, 0, stream>>>(x, px);
    pack_w_kernel<<<COUT, 256, 0, stream>>>(wt, pw, alpha);
    conv_kernel<<<NIMG * (HH / 2), 256, 0, stream>>>(px, pw, alpha, out);
}

// Round 2
// 259.177 us; speedup vs baseline: 1.0114x; 1.0114x over previous
//
#include <hip/hip_runtime.h>
#include <stdint.h>

#define CIN   256
#define COUT  128
#define HH    128
#define WW    128
#define NIMG  16

typedef unsigned long long u64;

// ---------------------------------------------------------------------------
// Pack sign bits of x: px[(n*HH + h)*WW + w][word 0..3], bit (c&63) of word
// (c>>6) is (x[n][c][h][w] > 0). Position-major, 4 u64 per position.
// Memory-bound: reads 256 MiB fp32, writes 8 MiB packed.
// ---------------------------------------------------------------------------
__global__ __launch_bounds__(256) void pack_x_kernel(const float* __restrict__ x,
                                                     u64* __restrict__ px) {
    int t = blockIdx.x * 256 + threadIdx.x;   // position id: n*16384 + h*128 + w
    int w = t & (WW - 1);
    int h = (t >> 7) & (HH - 1);
    int n = t >> 14;
    const float* xp = x + (size_t)n * CIN * HH * WW + (size_t)h * WW + w;
    u64 words[4];
#pragma unroll
    for (int wd = 0; wd < 4; ++wd) {
        u64 acc = 0;
#pragma unroll 16
        for (int cc = 0; cc < 64; ++cc) {
            float v = xp[(size_t)(wd * 64 + cc) * (HH * WW)];
            acc |= (u64)(v > 0.0f) << cc;
        }
        words[wd] = acc;
    }
    ulonglong2* o = reinterpret_cast<ulonglong2*>(px + (size_t)t * 4);
    o[0] = make_ulonglong2(words[0], words[1]);
    o[1] = make_ulonglong2(words[2], words[3]);
}

// ---------------------------------------------------------------------------
// Pack weight sign bits + alpha. One block per co; thread = channel c.
// pw[co*36 + tap*4 + word], tap = kh*3+kw. alpha[co] = mean|W| over 2304.
// ---------------------------------------------------------------------------
__global__ __launch_bounds__(256) void pack_w_kernel(const float* __restrict__ wt,
                                                     u64* __restrict__ pw,
                                                     float* __restrict__ alpha) {
    int co = blockIdx.x;
    int c  = threadIdx.x;        // 0..255 = input channel
    int lane = c & 63;
    int word = c >> 6;
    const float* wp = wt + ((size_t)co * CIN + c) * 9;
    float vals[9];
    float asum = 0.0f;
#pragma unroll
    for (int k = 0; k < 9; ++k) { vals[k] = wp[k]; asum += fabsf(vals[k]); }
#pragma unroll
    for (int k = 0; k < 9; ++k) {
        u64 m = __ballot(vals[k] > 0.0f);
        if (lane == 0) pw[co * 36 + k * 4 + word] = m;
    }
    __shared__ float red[4];
    for (int off = 32; off > 0; off >>= 1) asum += __shfl_down(asum, off);
    if (lane == 0) red[word] = asum;
    __syncthreads();
    if (c == 0) alpha[co] = (red[0] + red[1] + red[2] + red[3]) * (1.0f / 2304.0f);
}

// ---------------------------------------------------------------------------
// XNOR conv v2. R1 forensics: VGPR_Count=52 < 72 needed for xin residency =>
// compiler sank the px loads into the co-loop (2304 cached vmem reloads per
// thread, vmcnt stalls => VALUBusy 74.6%). Fix: inline-asm pin each xin u64
// ("+v" keep-alive) so the 36 input words stay in VGPRs across all 128 co.
// Weights stay in LDS (broadcast ds_read_b128, 0 bank conflicts measured).
// Border taps handled by per-tap AND masks (uniform hot loop).
// out[n][co][h][w] = (256*nv - 2*mismatch) * alpha[w]   (alpha by WIDTH!)
// ---------------------------------------------------------------------------
__global__ __launch_bounds__(256, 4) void conv_kernel(const u64* __restrict__ px,
                                                      const u64* __restrict__ pw,
                                                      const float* __restrict__ alpha,
                                                      float* __restrict__ out) {
    __shared__ __align__(16) u64 wlds[COUT * 36];   // 36 KiB
    for (int i = threadIdx.x; i < COUT * 36; i += 256) wlds[i] = pw[i];

    int tid = threadIdx.x;
    int w  = tid & (WW - 1);
    int hh = tid >> 7;                 // 0/1: two rows per block
    int bid = blockIdx.x;              // 0..1023 = n*64 + hpair
    int h = ((bid & 63) << 1) | hh;
    int n = bid >> 6;

    u64 xin[9][4];
    uint32_t vmask[9];
    int nv = 0;
#pragma unroll
    for (int dh = -1; dh <= 1; ++dh) {
#pragma unroll
        for (int dw = -1; dw <= 1; ++dw) {
            int k = (dh + 1) * 3 + (dw + 1);
            int hn = h + dh, wn = w + dw;
            bool valid = (hn >= 0) && (hn < HH) && (wn >= 0) && (wn < WW);
            vmask[k] = valid ? 0xFFFFFFFFu : 0u;
            nv += valid ? 1 : 0;
            // Clamped address, unconditional coalesced load, then mask data.
            int hc = min(max(hn, 0), HH - 1);
            int wc = min(max(wn, 0), WW - 1);
            const ulonglong2* p = reinterpret_cast<const ulonglong2*>(
                px + ((size_t)(n * HH + hc) * WW + wc) * 4);
            ulonglong2 a = p[0], b = p[1];
            u64 m64 = valid ? ~0ull : 0ull;
            xin[k][0] = a.x & m64; xin[k][1] = a.y & m64;
            xin[k][2] = b.x & m64; xin[k][3] = b.y & m64;
        }
    }
    // Pin the 36 input words into VGPRs: forbid the compiler from sinking
    // these loads into the co-loop (R1's 52-VGPR pathology).
#pragma unroll
    for (int k = 0; k < 9; ++k)
#pragma unroll
        for (int j = 0; j < 4; ++j)
            asm volatile("" : "+v"(xin[k][j]));

    __syncthreads();   // LDS weight stage complete

    int base = nv << 8;                 // 256 * valid taps
    float aw = alpha[w];                // faithful broadcast: alpha[WIDTH]
    float* op = out + (size_t)n * COUT * HH * WW + (size_t)h * WW + w;

    for (int co = 0; co < COUT; ++co) {
        const ulonglong2* wp2 = reinterpret_cast<const ulonglong2*>(&wlds[co * 36]);
        int M = 0;
#pragma unroll
        for (int k = 0; k < 9; ++k) {
            ulonglong2 wa = wp2[k * 2];
            ulonglong2 wb = wp2[k * 2 + 1];
            int c = __popcll(xin[k][0] ^ wa.x);
            c += __popcll(xin[k][1] ^ wa.y);
            c += __popcll(xin[k][2] ^ wb.x);
            c += __popcll(xin[k][3] ^ wb.y);
            M += c & (int)vmask[k];     // zero out OOB taps
        }
        op[(size_t)co * (HH * WW)] = (float)(base - 2 * M) * aw;
    }
}

extern "C" void kernel_launch(void* const* d_in, const int* in_sizes, int n_in,
                              void* d_out, int out_size, void* d_ws, size_t ws_size,
                              hipStream_t stream) {
    const float* x  = (const float*)d_in[0];
    const float* wt = (const float*)d_in[1];
    float* out = (float*)d_out;

    char* ws = (char*)d_ws;
    const size_t PX_BYTES = (size_t)NIMG * HH * WW * 4 * sizeof(u64);  // 8 MiB
    const size_t PW_BYTES = (size_t)COUT * 36 * sizeof(u64);           // 36 KiB
    if (ws_size < PX_BYTES + PW_BYTES + 512) return;  // workspace too small
    u64*   px    = (u64*)ws;
    u64*   pw    = (u64*)(ws + PX_BYTES);
    float* alpha = (float*)(ws + PX_BYTES + PW_BYTES);

    pack_x_kernel<<<NIMG * HH * WW / 256, 256, 0, stream>>>(x, px);
    pack_w_kernel<<<COUT, 256, 0, stream>>>(wt, pw, alpha);
    conv_kernel<<<NIMG * (HH / 2), 256, 0, stream>>>(px, pw, alpha, out);
}